// Round 2
// baseline (99.694 us; speedup 1.0000x reference)
//
#include <hip/hip_runtime.h>
#include <hip/hip_bf16.h>

// B=32, H=28, W=28, C=512 fp32 input. Output [32, 29, 29, 1] fp32.
// out2d[i][j] = clipped-window box sum of fsq; fsq[h][w] = sum_c x[0,h,w,c]^2.
// Batch dim is a broadcast. Single fused kernel, last-block-done pattern.

#define HH 28
#define WW 28
#define CC 512
#define BB 32
#define NHW (HH * WW)            // 784
#define OH (HH + 1)              // 29
#define OW (WW + 1)              // 29
#define OUTHW (OH * OW)          // 841

__global__ void __launch_bounds__(256)
fused_bsq_kernel(const float* __restrict__ x, float* __restrict__ out,
                 float* __restrict__ fsq, unsigned int* __restrict__ counter) {
    const int hw = blockIdx.x;        // [0, 784)
    const int t  = threadIdx.x;       // [0, 256)

    // ---- phase 1: sum_c x[0,hw,c]^2 ; 256 threads x float2 = 512 channels ----
    float2 v = reinterpret_cast<const float2*>(x + (size_t)hw * CC)[t];
    float s = v.x * v.x + v.y * v.y;
    #pragma unroll
    for (int off = 32; off > 0; off >>= 1)
        s += __shfl_down(s, off, 64);
    __shared__ float part[4];
    __shared__ int lastFlag;
    if ((t & 63) == 0) part[t >> 6] = s;
    __syncthreads();
    if (t == 0) {
        fsq[hw] = part[0] + part[1] + part[2] + part[3];
        __threadfence();                          // release fsq write (device scope)
        unsigned r = atomicAdd(counter, 1u);      // device-scope by default
        lastFlag = (r == NHW - 1) ? 1 : 0;
    }
    __syncthreads();
    if (!lastFlag) return;                        // uniform per block
    __threadfence();                              // acquire: see all fsq writes

    // ---- phase 2 (finisher block only): integral image + box sums + broadcast ----
    __shared__ float I[OH][WW + 2];               // [29][30], +1 col pad
    if (t < OW) I[0][t] = 0.f;
    if (t < OH) I[t][0] = 0.f;
    for (int idx = t; idx < NHW; idx += 256) {
        int r = idx / WW, c = idx % WW;
        I[r + 1][c + 1] = fsq[idx];
    }
    __syncthreads();

    if (t < HH) {                                 // horizontal cumsum, 1 thread/row
        float s2 = 0.f;
        #pragma unroll
        for (int c = 1; c <= WW; ++c) { s2 += I[t + 1][c]; I[t + 1][c] = s2; }
    }
    __syncthreads();

    if (t < WW) {                                 // vertical cumsum, 1 thread/col
        float s2 = 0.f;
        #pragma unroll
        for (int r = 1; r <= HH; ++r) { s2 += I[r][t + 1]; I[r][t + 1] = s2; }
    }
    __syncthreads();

    __shared__ float o2[OUTHW];
    for (int idx = t; idx < OUTHW; idx += 256) {
        int i = idx / OW, j = idx % OW;
        int r0 = min(max(HH / 2 - i, 0), HH);
        int r1 = min(max(HH / 2 + HH - i, 0), HH);
        int c0 = min(max(WW / 2 - j, 0), WW);
        int c1 = min(max(WW / 2 + WW - j, 0), WW);
        o2[idx] = I[r1][c1] - I[r0][c1] - I[r1][c0] + I[r0][c0];
    }
    __syncthreads();

    for (int idx = t; idx < BB * OUTHW; idx += 256)
        out[idx] = o2[idx % OUTHW];
}

extern "C" void kernel_launch(void* const* d_in, const int* in_sizes, int n_in,
                              void* d_out, int out_size, void* d_ws, size_t ws_size,
                              hipStream_t stream) {
    const float* x = (const float*)d_in[0];
    float* out = (float*)d_out;
    float* fsq = (float*)d_ws;                                   // 784 floats
    unsigned int* counter = (unsigned int*)((char*)d_ws + 4096); // 4-byte counter

    // ws is re-poisoned to 0xAA before every launch; zero the counter.
    // hipMemsetAsync is graph-capturable (becomes a memset node).
    hipMemsetAsync(counter, 0, sizeof(unsigned int), stream);
    fused_bsq_kernel<<<NHW, 256, 0, stream>>>(x, out, fsq, counter);
}

// Round 4
// 83.062 us; speedup vs baseline: 1.2002x; 1.2002x over previous
//
#include <hip/hip_runtime.h>
#include <hip/hip_bf16.h>

// B=32, H=28, W=28, C=512 fp32 input. Output [32, 29, 29, 1] fp32.
// out2d[i][j] = clipped-window box sum of fsq; fsq[h][w] = sum_c x[0,h,w,c]^2.
// Batch dim is a broadcast. Two kernels (R1 structure; R2's atomic fuse cost
// +16us from 784-way same-address atomic serialization — reverted).

#define HH 28
#define WW 28
#define CC 512
#define BB 32
#define NHW (HH * WW)            // 784
#define OH (HH + 1)              // 29
#define OW (WW + 1)              // 29
#define OUTHW (OH * OW)          // 841

// Kernel 1: 196 blocks x 256 threads; wave w handles hw = blk*4 + w.
// No LDS, no syncthreads: per-wave shuffle reduce only.
__global__ void __launch_bounds__(256)
fsq_kernel(const float* __restrict__ x, float* __restrict__ fsq) {
    const int wave = threadIdx.x >> 6;
    const int lane = threadIdx.x & 63;
    const int hw = blockIdx.x * 4 + wave;            // [0, 784)
    const float4* p = reinterpret_cast<const float4*>(x + (size_t)hw * CC);
    float4 a = p[lane];        // bytes [16*lane, +16)        — unit stride
    float4 b = p[lane + 64];   // bytes [1024 + 16*lane, +16) — unit stride
    float s = a.x * a.x + a.y * a.y + a.z * a.z + a.w * a.w
            + b.x * b.x + b.y * b.y + b.z * b.z + b.w * b.w;
    #pragma unroll
    for (int off = 32; off > 0; off >>= 1)
        s += __shfl_down(s, off, 64);
    if (lane == 0) fsq[hw] = s;
}

// Kernel 2: single block. Integral image in LDS, box sums, broadcast write.
__global__ void __launch_bounds__(256)
box_kernel(const float* __restrict__ fsq, float* __restrict__ out) {
    __shared__ float I[OH][WW + 2];   // [29][30], +1 col pad
    __shared__ float o2[OUTHW];       // 841
    const int t = threadIdx.x;

    if (t < OW) I[0][t] = 0.f;
    if (t < OH) I[t][0] = 0.f;
    for (int idx = t; idx < NHW; idx += 256) {
        int r = idx / WW, c = idx % WW;
        I[r + 1][c + 1] = fsq[idx];
    }
    __syncthreads();

    if (t < HH) {                                 // horizontal cumsum, 1 thread/row
        float s = 0.f;
        #pragma unroll
        for (int c = 1; c <= WW; ++c) { s += I[t + 1][c]; I[t + 1][c] = s; }
    }
    __syncthreads();

    if (t < WW) {                                 // vertical cumsum, 1 thread/col
        float s = 0.f;
        #pragma unroll
        for (int r = 1; r <= HH; ++r) { s += I[r][t + 1]; I[r][t + 1] = s; }
    }
    __syncthreads();

    for (int idx = t; idx < OUTHW; idx += 256) {
        int i = idx / OW, j = idx % OW;
        int r0 = min(max(HH / 2 - i, 0), HH);
        int r1 = min(max(HH / 2 + HH - i, 0), HH);
        int c0 = min(max(WW / 2 - j, 0), WW);
        int c1 = min(max(WW / 2 + WW - j, 0), WW);
        o2[idx] = I[r1][c1] - I[r0][c1] - I[r1][c0] + I[r0][c0];
    }
    __syncthreads();

    for (int idx = t; idx < BB * OUTHW; idx += 256)
        out[idx] = o2[idx % OUTHW];
}

extern "C" void kernel_launch(void* const* d_in, const int* in_sizes, int n_in,
                              void* d_out, int out_size, void* d_ws, size_t ws_size,
                              hipStream_t stream) {
    const float* x = (const float*)d_in[0];
    float* out = (float*)d_out;
    float* fsq = (float*)d_ws;   // 784 floats

    fsq_kernel<<<NHW / 4, 256, 0, stream>>>(x, fsq);
    box_kernel<<<1, 256, 0, stream>>>(fsq, out);
}